// Round 1
// baseline (1540.367 us; speedup 1.0000x reference)
//
#include <hip/hip_runtime.h>
#include <hip/hip_bf16.h>

typedef __bf16 bf16x8 __attribute__((ext_vector_type(8)));
typedef float f32x4 __attribute__((ext_vector_type(4)));
typedef unsigned short ushort4v __attribute__((ext_vector_type(4)));

#define S_LEN 2048
#define DIM 1024
#define NH 16
#define NKV 8
#define HD 64
#define HID 2816

__device__ __forceinline__ unsigned short f2bf(float f) {
    union { float f; unsigned u; } v; v.f = f;
    unsigned r = v.u + 0x7fffu + ((v.u >> 16) & 1u);   // RNE
    return (unsigned short)(r >> 16);
}

// ---------------- embedding gather ----------------
__global__ __launch_bounds__(256) void embed_kernel(const int* __restrict__ tokens,
                                                    const float* __restrict__ emb,
                                                    float* __restrict__ h) {
    int s = blockIdx.x;
    int t = tokens[s];
    float4 v = *(const float4*)&emb[(size_t)t * DIM + threadIdx.x * 4];
    *(float4*)&h[(size_t)s * DIM + threadIdx.x * 4] = v;
}

// ---------------- rmsnorm (one block per row of 1024) ----------------
__global__ __launch_bounds__(256) void rmsnorm_kernel(const float* __restrict__ x,
                                                      const float* __restrict__ w,
                                                      float* __restrict__ out) {
    __shared__ float sred[4];
    int s = blockIdx.x;
    int tid = threadIdx.x;
    float4 v = *(const float4*)&x[(size_t)s * DIM + tid * 4];
    float ss = v.x * v.x + v.y * v.y + v.z * v.z + v.w * v.w;
#pragma unroll
    for (int off = 32; off; off >>= 1) ss += __shfl_down(ss, off);
    if ((tid & 63) == 0) sred[tid >> 6] = ss;
    __syncthreads();
    float tot = sred[0] + sred[1] + sred[2] + sred[3];
    float scale = rsqrtf(tot * (1.0f / DIM) + 1e-5f);
    float4 wv = *(const float4*)&w[tid * 4];
    float4 o;
    o.x = v.x * scale * wv.x; o.y = v.y * scale * wv.y;
    o.z = v.z * scale * wv.z; o.w = v.w * scale * wv.w;
    *(float4*)&out[(size_t)s * DIM + tid * 4] = o;
}

// ---------------- GEMM: C[MxN] = A[MxK] * B[KxN] (+addsrc), f32 in, bf16 MFMA ----------------
#define BM 128
#define BN 128
#define BKD 32
#define LDK 40   // padded LDS row stride (elements); 80B keeps 16B alignment for b128

__global__ __launch_bounds__(256) void gemm_bf16(const float* __restrict__ A,
                                                 const float* __restrict__ B,
                                                 float* __restrict__ C,
                                                 const float* __restrict__ addsrc,
                                                 int M, int N, int K) {
    __shared__ unsigned short As[BM * LDK];
    __shared__ unsigned short Bs[BN * LDK];   // stored transposed: Bs[n][k]
    int tid = threadIdx.x;
    int lane = tid & 63;
    int wid = tid >> 6;
    int wrow = wid >> 1, wcol = wid & 1;      // 2x2 waves, each 64x64
    int lr = lane & 15, lg = lane >> 4;
    const int m0 = blockIdx.x * BM, n0 = blockIdx.y * BN;

    f32x4 acc[4][4] = {};

    for (int k0 = 0; k0 < K; k0 += BKD) {
        // stage A: 128x32 f32 -> bf16, row-major [m][k]
#pragma unroll
        for (int i = 0; i < 4; ++i) {
            int id = tid + 256 * i;
            int k4 = id & 7, m = id >> 3;
            const float4 v = *(const float4*)&A[(size_t)(m0 + m) * K + k0 + k4 * 4];
            ushort4v b;
            b[0] = f2bf(v.x); b[1] = f2bf(v.y); b[2] = f2bf(v.z); b[3] = f2bf(v.w);
            *(ushort4v*)&As[m * LDK + k4 * 4] = b;
        }
        // stage B transposed: each thread loads 4 along K (coalesced across lanes in N)
#pragma unroll
        for (int i = 0; i < 4; ++i) {
            int id = tid + 256 * i;
            int n = id & 127, k4 = id >> 7;
            ushort4v b;
#pragma unroll
            for (int j = 0; j < 4; ++j)
                b[j] = f2bf(B[(size_t)(k0 + k4 * 4 + j) * N + n0 + n]);
            *(ushort4v*)&Bs[n * LDK + k4 * 4] = b;
        }
        __syncthreads();
        bf16x8 aF[4], bF[4];
#pragma unroll
        for (int mi = 0; mi < 4; ++mi)
            aF[mi] = *(const bf16x8*)&As[(wrow * 64 + mi * 16 + lr) * LDK + lg * 8];
#pragma unroll
        for (int ni = 0; ni < 4; ++ni)
            bF[ni] = *(const bf16x8*)&Bs[(wcol * 64 + ni * 16 + lr) * LDK + lg * 8];
#pragma unroll
        for (int mi = 0; mi < 4; ++mi)
#pragma unroll
            for (int ni = 0; ni < 4; ++ni)
                acc[mi][ni] = __builtin_amdgcn_mfma_f32_16x16x32_bf16(aF[mi], bF[ni], acc[mi][ni], 0, 0, 0);
        __syncthreads();
    }
    // epilogue: C/D layout col=lane&15, row=(lane>>4)*4+reg
#pragma unroll
    for (int mi = 0; mi < 4; ++mi)
#pragma unroll
        for (int ni = 0; ni < 4; ++ni) {
            int row = m0 + wrow * 64 + mi * 16 + lg * 4;
            int col = n0 + wcol * 64 + ni * 16 + lr;
#pragma unroll
            for (int r = 0; r < 4; ++r) {
                size_t idx = (size_t)(row + r) * N + col;
                float v = acc[mi][ni][r];
                if (addsrc) v += addsrc[idx];
                C[idx] = v;
            }
        }
}

// ---------------- RoPE + bf16 convert + k_news/v_news ----------------
// grid (S, 32): head 0-15 -> q rope, 16-23 -> k rope (+k_news), 24-31 -> v convert (+v_news)
__global__ __launch_bounds__(64) void rope_kernel(const float* __restrict__ q,
                                                  const float* __restrict__ k,
                                                  const float* __restrict__ v,
                                                  const float* __restrict__ fc,
                                                  const float* __restrict__ fs,
                                                  unsigned short* __restrict__ qb,
                                                  unsigned short* __restrict__ kb,
                                                  unsigned short* __restrict__ vb,
                                                  float* __restrict__ out, int layer) {
    const size_t LOGITS = (size_t)S_LEN * 32000;
    int s = blockIdx.x;
    int hh = blockIdx.y;
    int lane = threadIdx.x;
    if (hh < NH) {
        if (lane < 32) {
            const float* row = q + (size_t)s * (NH * HD) + hh * HD;
            float xr = row[2 * lane], xi = row[2 * lane + 1];
            float c = fc[s * 32 + lane], sn = fs[s * 32 + lane];
            size_t o = (size_t)s * (NH * HD) + hh * HD + lane;
            qb[o] = f2bf(xr * c - xi * sn);
            qb[o + 32] = f2bf(xr * sn + xi * c);
        }
    } else if (hh < NH + NKV) {
        int kh = hh - NH;
        if (lane < 32) {
            const float* row = k + (size_t)s * (NKV * HD) + kh * HD;
            float xr = row[2 * lane], xi = row[2 * lane + 1];
            float c = fc[s * 32 + lane], sn = fs[s * 32 + lane];
            float o0 = xr * c - xi * sn, o1 = xr * sn + xi * c;
            size_t o = (size_t)s * (NKV * HD) + kh * HD + lane;
            kb[o] = f2bf(o0);
            kb[o + 32] = f2bf(o1);
            if (s == S_LEN - 1) {
                float* kn = out + LOGITS + (size_t)layer * (NKV * HD) + kh * HD;
                kn[lane] = o0; kn[lane + 32] = o1;
            }
        }
    } else {
        int vh = hh - NH - NKV;
        const float* row = v + (size_t)s * (NKV * HD) + vh * HD;
        float val = row[lane];
        vb[(size_t)s * (NKV * HD) + vh * HD + lane] = f2bf(val);
        if (s == S_LEN - 1)
            out[LOGITS + (size_t)2 * (NKV * HD) + (size_t)layer * (NKV * HD) + vh * HD + lane] = val;
    }
}

// ---------------- flash attention: 1 wave per (16 q rows, head) ----------------
__global__ __launch_bounds__(64) void attn_kernel(const unsigned short* __restrict__ qb,
                                                  const unsigned short* __restrict__ kb,
                                                  const unsigned short* __restrict__ vb,
                                                  float* __restrict__ y) {
    int qt = blockIdx.x;     // 0..127
    int h = blockIdx.y;      // 0..15
    int kvh = h >> 1;        // rep = 2
    int lane = threadIdx.x;
    int lr = lane & 15, lg = lane >> 4;

    __shared__ unsigned short P[16 * 40];

    bf16x8 aq[2];
    int qrow = qt * 16 + lr;
#pragma unroll
    for (int c = 0; c < 2; ++c)
        aq[c] = *(const bf16x8*)&qb[(size_t)qrow * (NH * HD) + h * HD + c * 32 + lg * 8];

    f32x4 O[4] = {};
    float m[4], l[4];
#pragma unroll
    for (int r = 0; r < 4; ++r) { m[r] = -1e30f; l[r] = 0.f; }

    int ktiles = (qt * 16 + 15) / 32 + 1;
    for (int kt = 0; kt < ktiles; ++kt) {
        f32x4 s[2];
#pragma unroll
        for (int kc = 0; kc < 2; ++kc) {
            int key = kt * 32 + kc * 16 + lr;
            const unsigned short* krow = &kb[(size_t)key * (NKV * HD) + kvh * HD];
            bf16x8 bk0 = *(const bf16x8*)&krow[lg * 8];
            bf16x8 bk1 = *(const bf16x8*)&krow[32 + lg * 8];
            f32x4 z = {};
            z = __builtin_amdgcn_mfma_f32_16x16x32_bf16(aq[0], bk0, z, 0, 0, 0);
            z = __builtin_amdgcn_mfma_f32_16x16x32_bf16(aq[1], bk1, z, 0, 0, 0);
            s[kc] = z;
        }
        float pv[2][4];
#pragma unroll
        for (int r = 0; r < 4; ++r) {
            int row = qt * 16 + lg * 4 + r;
            float tm = -1e30f;
#pragma unroll
            for (int kc = 0; kc < 2; ++kc) {
                int key = kt * 32 + kc * 16 + lr;
                float val = s[kc][r] * 0.125f;
                if (key > row) val = -1e30f;
                pv[kc][r] = val;
                tm = fmaxf(tm, val);
            }
#pragma unroll
            for (int off = 1; off < 16; off <<= 1)
                tm = fmaxf(tm, __shfl_xor(tm, off));
            float mn = fmaxf(m[r], tm);
            float sc = __expf(m[r] - mn);
            l[r] *= sc;
#pragma unroll
            for (int n = 0; n < 4; ++n) O[n][r] *= sc;
            float rs = 0.f;
#pragma unroll
            for (int kc = 0; kc < 2; ++kc) {
                float p = __expf(pv[kc][r] - mn);
                pv[kc][r] = p;
                rs += p;
            }
#pragma unroll
            for (int off = 1; off < 16; off <<= 1)
                rs += __shfl_xor(rs, off);
            l[r] += rs;
            m[r] = mn;
        }
        // transpose P (C-layout -> A-frag layout) through LDS
#pragma unroll
        for (int r = 0; r < 4; ++r)
#pragma unroll
            for (int kc = 0; kc < 2; ++kc)
                P[(lg * 4 + r) * 40 + kc * 16 + lr] = f2bf(pv[kc][r]);
        __syncthreads();
        bf16x8 pa = *(const bf16x8*)&P[lr * 40 + lg * 8];
#pragma unroll
        for (int n = 0; n < 4; ++n) {
            unsigned short bvr[8];
#pragma unroll
            for (int i = 0; i < 8; ++i)
                bvr[i] = vb[(size_t)(kt * 32 + lg * 8 + i) * (NKV * HD) + kvh * HD + n * 16 + lr];
            bf16x8 bv = *(const bf16x8*)bvr;
            O[n] = __builtin_amdgcn_mfma_f32_16x16x32_bf16(pa, bv, O[n], 0, 0, 0);
        }
        __syncthreads();
    }
#pragma unroll
    for (int n = 0; n < 4; ++n)
#pragma unroll
        for (int r = 0; r < 4; ++r) {
            int row = qt * 16 + lg * 4 + r;
            y[(size_t)row * (NH * HD) + h * HD + n * 16 + lr] = O[n][r] / l[r];
        }
}

// ---------------- silu(g) * u -> g ----------------
__global__ __launch_bounds__(256) void silu_mul_kernel(float* __restrict__ g,
                                                       const float* __restrict__ u) {
    size_t i = (size_t)blockIdx.x * 256 + threadIdx.x;
    float4 a = ((const float4*)g)[i];
    float4 b = ((const float4*)u)[i];
    float4 o;
    o.x = a.x / (1.f + __expf(-a.x)) * b.x;
    o.y = a.y / (1.f + __expf(-a.y)) * b.y;
    o.z = a.z / (1.f + __expf(-a.z)) * b.z;
    o.w = a.w / (1.f + __expf(-a.w)) * b.w;
    ((float4*)g)[i] = o;
}

extern "C" void kernel_launch(void* const* d_in, const int* in_sizes, int n_in,
                              void* d_out, int out_size, void* d_ws, size_t ws_size,
                              hipStream_t stream) {
    const int* tokens = (const int*)d_in[0];
    const float* freqs_cos = (const float*)d_in[2];
    const float* freqs_sin = (const float*)d_in[3];
    const float* tok_emb = (const float*)d_in[4];
    const float* wq = (const float*)d_in[5];
    const float* wk = (const float*)d_in[6];
    const float* wv = (const float*)d_in[7];
    const float* wo = (const float*)d_in[8];
    const float* attn_norm_w = (const float*)d_in[9];
    const float* ffn_norm_w = (const float*)d_in[10];
    const float* w1 = (const float*)d_in[11];
    const float* w2 = (const float*)d_in[12];
    const float* w3 = (const float*)d_in[13];
    const float* final_norm_w = (const float*)d_in[14];
    const float* out_w = (const float*)d_in[15];
    float* out = (float*)d_out;

    const size_t SD = (size_t)S_LEN * DIM;          // 2,097,152
    const size_t SKV = (size_t)S_LEN * NKV * HD;    // 1,048,576
    const size_t SH = (size_t)S_LEN * HID;          // 5,767,168

    float* h  = (float*)d_ws;
    float* xn = h + SD;
    float* q  = xn + SD;
    float* kx = q + SD;
    float* vx = kx + SKV;
    float* y  = vx + SKV;
    float* g  = y + SD;
    float* u  = g + SH;
    unsigned short* qb = (unsigned short*)(u + SH);
    unsigned short* kb = qb + SD;
    unsigned short* vb = kb + SKV;

    embed_kernel<<<S_LEN, 256, 0, stream>>>(tokens, tok_emb, h);
    for (int l = 0; l < 2; ++l) {
        rmsnorm_kernel<<<S_LEN, 256, 0, stream>>>(h, attn_norm_w + l * DIM, xn);
        gemm_bf16<<<dim3(16, 8), 256, 0, stream>>>(xn, wq + (size_t)l * DIM * (NH * HD), q, nullptr, S_LEN, NH * HD, DIM);
        gemm_bf16<<<dim3(16, 4), 256, 0, stream>>>(xn, wk + (size_t)l * DIM * (NKV * HD), kx, nullptr, S_LEN, NKV * HD, DIM);
        gemm_bf16<<<dim3(16, 4), 256, 0, stream>>>(xn, wv + (size_t)l * DIM * (NKV * HD), vx, nullptr, S_LEN, NKV * HD, DIM);
        rope_kernel<<<dim3(S_LEN, 32), 64, 0, stream>>>(q, kx, vx, freqs_cos, freqs_sin, qb, kb, vb, out, l);
        attn_kernel<<<dim3(S_LEN / 16, NH), 64, 0, stream>>>(qb, kb, vb, y);
        gemm_bf16<<<dim3(16, 8), 256, 0, stream>>>(y, wo + (size_t)l * (NH * HD) * DIM, h, h, S_LEN, DIM, NH * HD);
        rmsnorm_kernel<<<S_LEN, 256, 0, stream>>>(h, ffn_norm_w + l * DIM, xn);
        gemm_bf16<<<dim3(16, 22), 256, 0, stream>>>(xn, w1 + (size_t)l * DIM * HID, g, nullptr, S_LEN, HID, DIM);
        gemm_bf16<<<dim3(16, 22), 256, 0, stream>>>(xn, w3 + (size_t)l * DIM * HID, u, nullptr, S_LEN, HID, DIM);
        silu_mul_kernel<<<(int)(SH / 4 / 256), 256, 0, stream>>>(g, u);
        gemm_bf16<<<dim3(16, 8), 256, 0, stream>>>(g, w2 + (size_t)l * HID * DIM, h, h, S_LEN, DIM, HID);
    }
    rmsnorm_kernel<<<S_LEN, 256, 0, stream>>>(h, final_norm_w, xn);
    gemm_bf16<<<dim3(16, 250), 256, 0, stream>>>(xn, out_w, out, nullptr, S_LEN, 32000, DIM);
}

// Round 2
// 973.068 us; speedup vs baseline: 1.5830x; 1.5830x over previous
//
#include <hip/hip_runtime.h>
#include <hip/hip_bf16.h>

typedef __bf16 bf16x8 __attribute__((ext_vector_type(8)));
typedef float f32x4 __attribute__((ext_vector_type(4)));
typedef unsigned short ushort4v __attribute__((ext_vector_type(4)));
typedef unsigned short ushort8v __attribute__((ext_vector_type(8)));

#define S_LEN 2048
#define DIM 1024
#define NH 16
#define NKV 8
#define HD 64
#define HID 2816

__device__ __forceinline__ unsigned short f2bf(float f) {
    union { float f; unsigned u; } v; v.f = f;
    unsigned r = v.u + 0x7fffu + ((v.u >> 16) & 1u);   // RNE
    return (unsigned short)(r >> 16);
}
__device__ __forceinline__ float bf2f(unsigned short u) {
    union { unsigned u; float f; } v; v.u = (unsigned)u << 16; return v.f;
}

__device__ __forceinline__ void gload16(const unsigned short* g, unsigned short* l) {
    __builtin_amdgcn_global_load_lds(
        (const __attribute__((address_space(1))) unsigned int*)g,
        (__attribute__((address_space(3))) unsigned int*)l,
        16, 0, 0);
}

// ---------------- embedding gather ----------------
__global__ __launch_bounds__(256) void embed_kernel(const int* __restrict__ tokens,
                                                    const float* __restrict__ emb,
                                                    float* __restrict__ h) {
    int s = blockIdx.x;
    int t = tokens[s];
    float4 v = *(const float4*)&emb[(size_t)t * DIM + threadIdx.x * 4];
    *(float4*)&h[(size_t)s * DIM + threadIdx.x * 4] = v;
}

// ---------------- rmsnorm: f32 in -> bf16 out ----------------
__global__ __launch_bounds__(256) void rmsnorm_kernel(const float* __restrict__ x,
                                                      const float* __restrict__ w,
                                                      unsigned short* __restrict__ out) {
    __shared__ float sred[4];
    int s = blockIdx.x;
    int tid = threadIdx.x;
    float4 v = *(const float4*)&x[(size_t)s * DIM + tid * 4];
    float ss = v.x * v.x + v.y * v.y + v.z * v.z + v.w * v.w;
#pragma unroll
    for (int off = 32; off; off >>= 1) ss += __shfl_down(ss, off);
    if ((tid & 63) == 0) sred[tid >> 6] = ss;
    __syncthreads();
    float tot = sred[0] + sred[1] + sred[2] + sred[3];
    float scale = rsqrtf(tot * (1.0f / DIM) + 1e-5f);
    float4 wv = *(const float4*)&w[tid * 4];
    ushort4v o;
    o[0] = f2bf(v.x * scale * wv.x); o[1] = f2bf(v.y * scale * wv.y);
    o[2] = f2bf(v.z * scale * wv.z); o[3] = f2bf(v.w * scale * wv.w);
    *(ushort4v*)&out[(size_t)s * DIM + tid * 4] = o;
}

// ---------------- transpose + convert: f32 [K][N] -> bf16 [N][K] ----------------
__global__ __launch_bounds__(256) void transpose_w(const float* __restrict__ in,
                                                   unsigned short* __restrict__ out,
                                                   int K, int N) {
    __shared__ unsigned short t[64][68];
    int n0 = blockIdx.x * 64, k0 = blockIdx.y * 64;
    int tid = threadIdx.x;
    int tn = tid & 15, tk = tid >> 4;
#pragma unroll
    for (int p = 0; p < 4; ++p) {
        int k = tk + p * 16;
        float4 v = *(const float4*)&in[(size_t)(k0 + k) * N + n0 + tn * 4];
        t[tn * 4 + 0][k] = f2bf(v.x);
        t[tn * 4 + 1][k] = f2bf(v.y);
        t[tn * 4 + 2][k] = f2bf(v.z);
        t[tn * 4 + 3][k] = f2bf(v.w);
    }
    __syncthreads();
    int wk = tid & 15, wn = tid >> 4;
#pragma unroll
    for (int p = 0; p < 4; ++p) {
        int n = wn + p * 16;
        ushort4v v;
        v[0] = t[n][wk * 4]; v[1] = t[n][wk * 4 + 1];
        v[2] = t[n][wk * 4 + 2]; v[3] = t[n][wk * 4 + 3];
        *(ushort4v*)&out[(size_t)(n0 + n) * K + k0 + wk * 4] = v;
    }
}

// ---------------- GEMM (m97 structure): A bf16 [M][lda], Bt bf16 [N][K] ----------------
// C = A*B^T (f32 or bf16 out), optional f32 residual add.
__global__ __launch_bounds__(256) void gemm_tn(const unsigned short* __restrict__ A, int lda,
                                               const unsigned short* __restrict__ Bt,
                                               float* __restrict__ Cf,
                                               unsigned short* __restrict__ Cb,
                                               const float* __restrict__ addsrc,
                                               int N, int K) {
    __shared__ unsigned short As[128 * 64];
    __shared__ unsigned short Bs[128 * 64];
    int tid = threadIdx.x;
    int lane = tid & 63;
    int wid = tid >> 6;
    int wrow = wid >> 1, wcol = wid & 1;      // 2x2 waves, each 64x64
    int lr = lane & 15, lg = lane >> 4;
    const int m0 = blockIdx.x * 128, n0 = blockIdx.y * 128;

    // staging: chunk c = wid*4+i covers 8 rows; lane covers (lane/8)th row, (lane%8)*8 elems
    const unsigned short* aG = A + (size_t)(m0 + wid * 32 + (lane >> 3)) * lda + (lane & 7) * 8;
    const unsigned short* bG = Bt + (size_t)(n0 + wid * 32 + (lane >> 3)) * K + (lane & 7) * 8;
    unsigned short* aL = As + wid * 2048;
    unsigned short* bL = Bs + wid * 2048;

    f32x4 acc[4][4] = {};

    for (int k0 = 0; k0 < K; k0 += 64) {
#pragma unroll
        for (int i = 0; i < 4; ++i)
            gload16(aG + (size_t)(i * 8) * lda + k0, aL + i * 512);
#pragma unroll
        for (int i = 0; i < 4; ++i)
            gload16(bG + (size_t)(i * 8) * K + k0, bL + i * 512);
        __syncthreads();
#pragma unroll
        for (int kk = 0; kk < 2; ++kk) {
            bf16x8 aF[4], bF[4];
#pragma unroll
            for (int mi = 0; mi < 4; ++mi)
                aF[mi] = *(const bf16x8*)&As[(wrow * 64 + mi * 16 + lr) * 64 + kk * 32 + lg * 8];
#pragma unroll
            for (int ni = 0; ni < 4; ++ni)
                bF[ni] = *(const bf16x8*)&Bs[(wcol * 64 + ni * 16 + lr) * 64 + kk * 32 + lg * 8];
#pragma unroll
            for (int mi = 0; mi < 4; ++mi)
#pragma unroll
                for (int ni = 0; ni < 4; ++ni)
                    acc[mi][ni] = __builtin_amdgcn_mfma_f32_16x16x32_bf16(aF[mi], bF[ni], acc[mi][ni], 0, 0, 0);
        }
        __syncthreads();
    }
    // epilogue: C/D layout col=lane&15, row=(lane>>4)*4+reg
#pragma unroll
    for (int mi = 0; mi < 4; ++mi)
#pragma unroll
        for (int ni = 0; ni < 4; ++ni) {
            int row = m0 + wrow * 64 + mi * 16 + lg * 4;
            int col = n0 + wcol * 64 + ni * 16 + lr;
#pragma unroll
            for (int r = 0; r < 4; ++r) {
                size_t idx = (size_t)(row + r) * N + col;
                float v = acc[mi][ni][r];
                if (addsrc) v += addsrc[idx];
                if (Cb) Cb[idx] = f2bf(v);
                else    Cf[idx] = v;
            }
        }
}

// ---------------- RoPE on fused qkv f32 [S][2048]; writes bf16 qb/kb/vb + news ----------------
__global__ __launch_bounds__(64) void rope_kernel(const float* __restrict__ qkv,
                                                  const float* __restrict__ fc,
                                                  const float* __restrict__ fs,
                                                  unsigned short* __restrict__ qb,
                                                  unsigned short* __restrict__ kb,
                                                  unsigned short* __restrict__ vb,
                                                  float* __restrict__ out, int layer) {
    const size_t LOGITS = (size_t)S_LEN * 32000;
    int s = blockIdx.x;
    int hh = blockIdx.y;
    int lane = threadIdx.x;
    const float* base = qkv + (size_t)s * 2048;
    if (hh < NH) {
        if (lane < 32) {
            const float* row = base + hh * HD;
            float xr = row[2 * lane], xi = row[2 * lane + 1];
            float c = fc[s * 32 + lane], sn = fs[s * 32 + lane];
            size_t o = (size_t)s * (NH * HD) + hh * HD + lane;
            qb[o] = f2bf(xr * c - xi * sn);
            qb[o + 32] = f2bf(xr * sn + xi * c);
        }
    } else if (hh < NH + NKV) {
        int kh = hh - NH;
        if (lane < 32) {
            const float* row = base + 1024 + kh * HD;
            float xr = row[2 * lane], xi = row[2 * lane + 1];
            float c = fc[s * 32 + lane], sn = fs[s * 32 + lane];
            float o0 = xr * c - xi * sn, o1 = xr * sn + xi * c;
            size_t o = (size_t)s * (NKV * HD) + kh * HD + lane;
            kb[o] = f2bf(o0);
            kb[o + 32] = f2bf(o1);
            if (s == S_LEN - 1) {
                float* kn = out + LOGITS + (size_t)layer * (NKV * HD) + kh * HD;
                kn[lane] = o0; kn[lane + 32] = o1;
            }
        }
    } else {
        int vh = hh - NH - NKV;
        const float* row = base + 1536 + vh * HD;
        float val = row[lane];
        vb[(size_t)s * (NKV * HD) + vh * HD + lane] = f2bf(val);
        if (s == S_LEN - 1)
            out[LOGITS + (size_t)2 * (NKV * HD) + (size_t)layer * (NKV * HD) + vh * HD + lane] = val;
    }
}

// ---------------- flash attention: 1 wave per (16 q rows, head); bf16 y out ----------------
__global__ __launch_bounds__(64) void attn_kernel(const unsigned short* __restrict__ qb,
                                                  const unsigned short* __restrict__ kb,
                                                  const unsigned short* __restrict__ vb,
                                                  unsigned short* __restrict__ yb) {
    int qt = blockIdx.x;     // 0..127
    int h = blockIdx.y;      // 0..15
    int kvh = h >> 1;        // rep = 2
    int lane = threadIdx.x;
    int lr = lane & 15, lg = lane >> 4;

    __shared__ unsigned short P[16 * 40];

    bf16x8 aq[2];
    int qrow = qt * 16 + lr;
#pragma unroll
    for (int c = 0; c < 2; ++c)
        aq[c] = *(const bf16x8*)&qb[(size_t)qrow * (NH * HD) + h * HD + c * 32 + lg * 8];

    f32x4 O[4] = {};
    float m[4], l[4];
#pragma unroll
    for (int r = 0; r < 4; ++r) { m[r] = -1e30f; l[r] = 0.f; }

    int ktiles = (qt * 16 + 15) / 32 + 1;
    for (int kt = 0; kt < ktiles; ++kt) {
        f32x4 s[2];
#pragma unroll
        for (int kc = 0; kc < 2; ++kc) {
            int key = kt * 32 + kc * 16 + lr;
            const unsigned short* krow = &kb[(size_t)key * (NKV * HD) + kvh * HD];
            bf16x8 bk0 = *(const bf16x8*)&krow[lg * 8];
            bf16x8 bk1 = *(const bf16x8*)&krow[32 + lg * 8];
            f32x4 z = {};
            z = __builtin_amdgcn_mfma_f32_16x16x32_bf16(aq[0], bk0, z, 0, 0, 0);
            z = __builtin_amdgcn_mfma_f32_16x16x32_bf16(aq[1], bk1, z, 0, 0, 0);
            s[kc] = z;
        }
        float pv[2][4];
#pragma unroll
        for (int r = 0; r < 4; ++r) {
            int row = qt * 16 + lg * 4 + r;
            float tm = -1e30f;
#pragma unroll
            for (int kc = 0; kc < 2; ++kc) {
                int key = kt * 32 + kc * 16 + lr;
                float val = s[kc][r] * 0.125f;
                if (key > row) val = -1e30f;
                pv[kc][r] = val;
                tm = fmaxf(tm, val);
            }
#pragma unroll
            for (int off = 1; off < 16; off <<= 1)
                tm = fmaxf(tm, __shfl_xor(tm, off));
            float mn = fmaxf(m[r], tm);
            float sc = __expf(m[r] - mn);
            l[r] *= sc;
#pragma unroll
            for (int n = 0; n < 4; ++n) O[n][r] *= sc;
            float rs = 0.f;
#pragma unroll
            for (int kc = 0; kc < 2; ++kc) {
                float p = __expf(pv[kc][r] - mn);
                pv[kc][r] = p;
                rs += p;
            }
#pragma unroll
            for (int off = 1; off < 16; off <<= 1)
                rs += __shfl_xor(rs, off);
            l[r] += rs;
            m[r] = mn;
        }
#pragma unroll
        for (int r = 0; r < 4; ++r)
#pragma unroll
            for (int kc = 0; kc < 2; ++kc)
                P[(lg * 4 + r) * 40 + kc * 16 + lr] = f2bf(pv[kc][r]);
        __syncthreads();
        bf16x8 pa = *(const bf16x8*)&P[lr * 40 + lg * 8];
#pragma unroll
        for (int n = 0; n < 4; ++n) {
            unsigned short bvr[8];
#pragma unroll
            for (int i = 0; i < 8; ++i)
                bvr[i] = vb[(size_t)(kt * 32 + lg * 8 + i) * (NKV * HD) + kvh * HD + n * 16 + lr];
            bf16x8 bv = *(const bf16x8*)bvr;
            O[n] = __builtin_amdgcn_mfma_f32_16x16x32_bf16(pa, bv, O[n], 0, 0, 0);
        }
        __syncthreads();
    }
#pragma unroll
    for (int n = 0; n < 4; ++n)
#pragma unroll
        for (int r = 0; r < 4; ++r) {
            int row = qt * 16 + lg * 4 + r;
            yb[(size_t)row * (NH * HD) + h * HD + n * 16 + lr] = f2bf(O[n][r] / l[r]);
        }
}

// ---------------- silu(g)*u in fused gu bf16 [S][5632], in place into g half ----------------
__global__ __launch_bounds__(256) void silu_mul_kernel(unsigned short* __restrict__ gu) {
    size_t idx = (size_t)blockIdx.x * 256 + threadIdx.x;   // over S * (2816/8)
    int s = (int)(idx / 352);
    int c8 = (int)(idx % 352);
    unsigned short* gp = gu + (size_t)s * 5632 + c8 * 8;
    ushort8v a = *(const ushort8v*)gp;
    ushort8v b = *(const ushort8v*)(gp + 2816);
#pragma unroll
    for (int j = 0; j < 8; ++j) {
        float x = bf2f(a[j]), y = bf2f(b[j]);
        a[j] = f2bf(x / (1.f + __expf(-x)) * y);
    }
    *(ushort8v*)gp = a;
}

extern "C" void kernel_launch(void* const* d_in, const int* in_sizes, int n_in,
                              void* d_out, int out_size, void* d_ws, size_t ws_size,
                              hipStream_t stream) {
    const int* tokens = (const int*)d_in[0];
    const float* freqs_cos = (const float*)d_in[2];
    const float* freqs_sin = (const float*)d_in[3];
    const float* tok_emb = (const float*)d_in[4];
    const float* wq = (const float*)d_in[5];
    const float* wk = (const float*)d_in[6];
    const float* wv = (const float*)d_in[7];
    const float* wo = (const float*)d_in[8];
    const float* attn_norm_w = (const float*)d_in[9];
    const float* ffn_norm_w = (const float*)d_in[10];
    const float* w1 = (const float*)d_in[11];
    const float* w2 = (const float*)d_in[12];
    const float* w3 = (const float*)d_in[13];
    const float* final_norm_w = (const float*)d_in[14];
    const float* out_w = (const float*)d_in[15];
    float* out = (float*)d_out;

    const size_t SD = (size_t)S_LEN * DIM;          // 2,097,152
    const size_t SKV = (size_t)S_LEN * NKV * HD;    // 1,048,576

    char* p = (char*)d_ws;
    auto take = [&](size_t bytes) { char* r = p; p += (bytes + 255) & ~(size_t)255; return r; };
    float* h            = (float*)take(SD * 4);
    unsigned short* xnb = (unsigned short*)take(SD * 2);
    char* uni = p;
    // per-layer union members
    float* qkvf         = (float*)uni;                                  // 16 MB
    unsigned short* qb  = (unsigned short*)(uni + 17039360);            // 4 MB
    unsigned short* kb  = qb + SD;                                      // 2 MB
    unsigned short* vb  = kb + SKV;                                     // 2 MB
    unsigned short* ybv = vb + SKV;                                     // 4 MB
    unsigned short* gu  = ybv + SD;                                     // 23 MB
    unsigned short* wT  = gu + (size_t)S_LEN * 5632;                    // 11.5 MB
    // final phase: out_w^T overlays the whole union
    unsigned short* owT = (unsigned short*)uni;                         // 65.5 MB

    embed_kernel<<<S_LEN, 256, 0, stream>>>(tokens, tok_emb, h);
    for (int l = 0; l < 2; ++l) {
        rmsnorm_kernel<<<S_LEN, 256, 0, stream>>>(h, attn_norm_w + l * DIM, xnb);
        // qkv fused: wT rows 0..1023=wq^T, 1024..1535=wk^T, 1536..2047=wv^T
        transpose_w<<<dim3(16, 16), 256, 0, stream>>>(wq + (size_t)l * DIM * 1024, wT, DIM, 1024);
        transpose_w<<<dim3(8, 16), 256, 0, stream>>>(wk + (size_t)l * DIM * 512, wT + (size_t)1024 * DIM, DIM, 512);
        transpose_w<<<dim3(8, 16), 256, 0, stream>>>(wv + (size_t)l * DIM * 512, wT + (size_t)1536 * DIM, DIM, 512);
        gemm_tn<<<dim3(16, 16), 256, 0, stream>>>(xnb, DIM, wT, qkvf, nullptr, nullptr, 2048, DIM);
        rope_kernel<<<dim3(S_LEN, 32), 64, 0, stream>>>(qkvf, freqs_cos, freqs_sin, qb, kb, vb, out, l);
        attn_kernel<<<dim3(S_LEN / 16, NH), 64, 0, stream>>>(qb, kb, vb, ybv);
        transpose_w<<<dim3(16, 16), 256, 0, stream>>>(wo + (size_t)l * 1024 * DIM, wT, 1024, DIM);
        gemm_tn<<<dim3(16, 8), 256, 0, stream>>>(ybv, 1024, wT, h, nullptr, h, DIM, 1024);
        rmsnorm_kernel<<<S_LEN, 256, 0, stream>>>(h, ffn_norm_w + l * DIM, xnb);
        // w1 | w3 fused along N
        transpose_w<<<dim3(44, 16), 256, 0, stream>>>(w1 + (size_t)l * DIM * HID, wT, DIM, HID);
        transpose_w<<<dim3(44, 16), 256, 0, stream>>>(w3 + (size_t)l * DIM * HID, wT + (size_t)HID * DIM, DIM, HID);
        gemm_tn<<<dim3(16, 44), 256, 0, stream>>>(xnb, DIM, wT, nullptr, gu, nullptr, 5632, DIM);
        silu_mul_kernel<<<(S_LEN * 352) / 256, 256, 0, stream>>>(gu);
        transpose_w<<<dim3(16, 44), 256, 0, stream>>>(w2 + (size_t)l * HID * 1024, wT, HID, 1024);
        gemm_tn<<<dim3(16, 8), 256, 0, stream>>>(gu, 5632, wT, h, nullptr, h, DIM, HID);
    }
    rmsnorm_kernel<<<S_LEN, 256, 0, stream>>>(h, final_norm_w, xnb);
    transpose_w<<<dim3(500, 16), 256, 0, stream>>>(out_w, owT, DIM, 32000);
    gemm_tn<<<dim3(16, 250), 256, 0, stream>>>(xnb, DIM, owT, out, nullptr, nullptr, 32000, DIM);
}

// Round 3
// 956.020 us; speedup vs baseline: 1.6112x; 1.0178x over previous
//
#include <hip/hip_runtime.h>
#include <hip/hip_bf16.h>

typedef __bf16 bf16x8 __attribute__((ext_vector_type(8)));
typedef float f32x4 __attribute__((ext_vector_type(4)));
typedef unsigned short ushort4v __attribute__((ext_vector_type(4)));
typedef unsigned short ushort8v __attribute__((ext_vector_type(8)));

#define S_LEN 2048
#define DIM 1024
#define NH 16
#define NKV 8
#define HD 64
#define HID 2816

__device__ __forceinline__ unsigned short f2bf(float f) {
    union { float f; unsigned u; } v; v.f = f;
    unsigned r = v.u + 0x7fffu + ((v.u >> 16) & 1u);   // RNE
    return (unsigned short)(r >> 16);
}
__device__ __forceinline__ float bf2f(unsigned short u) {
    union { unsigned u; float f; } v; v.u = (unsigned)u << 16; return v.f;
}

__device__ __forceinline__ void gload16(const unsigned short* g, unsigned short* l) {
    __builtin_amdgcn_global_load_lds(
        (const __attribute__((address_space(1))) unsigned int*)g,
        (__attribute__((address_space(3))) unsigned int*)l,
        16, 0, 0);
}

union Frag { f32x4 f; bf16x8 h; };

__device__ __forceinline__ f32x4 lds_read_b128(unsigned addr) {
    f32x4 d;
    asm volatile("ds_read_b128 %0, %1" : "=v"(d) : "v"(addr));
    return d;
}

// ---------------- embedding gather ----------------
__global__ __launch_bounds__(256) void embed_kernel(const int* __restrict__ tokens,
                                                    const float* __restrict__ emb,
                                                    float* __restrict__ h) {
    int s = blockIdx.x;
    int t = tokens[s];
    float4 v = *(const float4*)&emb[(size_t)t * DIM + threadIdx.x * 4];
    *(float4*)&h[(size_t)s * DIM + threadIdx.x * 4] = v;
}

// ---------------- rmsnorm: f32 in -> bf16 out ----------------
__global__ __launch_bounds__(256) void rmsnorm_kernel(const float* __restrict__ x,
                                                      const float* __restrict__ w,
                                                      unsigned short* __restrict__ out) {
    __shared__ float sred[4];
    int s = blockIdx.x;
    int tid = threadIdx.x;
    float4 v = *(const float4*)&x[(size_t)s * DIM + tid * 4];
    float ss = v.x * v.x + v.y * v.y + v.z * v.z + v.w * v.w;
#pragma unroll
    for (int off = 32; off; off >>= 1) ss += __shfl_down(ss, off);
    if ((tid & 63) == 0) sred[tid >> 6] = ss;
    __syncthreads();
    float tot = sred[0] + sred[1] + sred[2] + sred[3];
    float scale = rsqrtf(tot * (1.0f / DIM) + 1e-5f);
    float4 wv = *(const float4*)&w[tid * 4];
    ushort4v o;
    o[0] = f2bf(v.x * scale * wv.x); o[1] = f2bf(v.y * scale * wv.y);
    o[2] = f2bf(v.z * scale * wv.z); o[3] = f2bf(v.w * scale * wv.w);
    *(ushort4v*)&out[(size_t)s * DIM + tid * 4] = o;
}

// ---------------- transpose + convert: f32 [K][N] -> bf16 [N][K] ----------------
__global__ __launch_bounds__(256) void transpose_w(const float* __restrict__ in,
                                                   unsigned short* __restrict__ out,
                                                   int K, int N) {
    __shared__ unsigned short t[64][68];
    int n0 = blockIdx.x * 64, k0 = blockIdx.y * 64;
    int tid = threadIdx.x;
    int tn = tid & 15, tk = tid >> 4;
#pragma unroll
    for (int p = 0; p < 4; ++p) {
        int k = tk + p * 16;
        float4 v = *(const float4*)&in[(size_t)(k0 + k) * N + n0 + tn * 4];
        t[tn * 4 + 0][k] = f2bf(v.x);
        t[tn * 4 + 1][k] = f2bf(v.y);
        t[tn * 4 + 2][k] = f2bf(v.z);
        t[tn * 4 + 3][k] = f2bf(v.w);
    }
    __syncthreads();
    int wk = tid & 15, wn = tid >> 4;
#pragma unroll
    for (int p = 0; p < 4; ++p) {
        int n = wn + p * 16;
        ushort4v v;
        v[0] = t[n][wk * 4]; v[1] = t[n][wk * 4 + 1];
        v[2] = t[n][wk * 4 + 2]; v[3] = t[n][wk * 4 + 3];
        *(ushort4v*)&out[(size_t)(n0 + n) * K + k0 + wk * 4] = v;
    }
}

// ---------------- bf16 transpose: [2048][512] -> [512][2048] (for V) ----------------
__global__ __launch_bounds__(256) void transpose_v(const unsigned short* __restrict__ in,
                                                   unsigned short* __restrict__ out) {
    __shared__ unsigned short t[64][72];
    int c0 = blockIdx.x * 64, s0 = blockIdx.y * 64;
    int tid = threadIdx.x;
    int tc = tid & 15, ts = tid >> 4;
#pragma unroll
    for (int p = 0; p < 4; ++p) {
        int s = ts + p * 16;
        ushort4v v = *(const ushort4v*)&in[(size_t)(s0 + s) * 512 + c0 + tc * 4];
        t[tc * 4 + 0][s] = v[0];
        t[tc * 4 + 1][s] = v[1];
        t[tc * 4 + 2][s] = v[2];
        t[tc * 4 + 3][s] = v[3];
    }
    __syncthreads();
    int ws_ = tid & 15, wc = tid >> 4;
#pragma unroll
    for (int p = 0; p < 4; ++p) {
        int c = wc + p * 16;
        ushort4v v;
        v[0] = t[c][ws_ * 4]; v[1] = t[c][ws_ * 4 + 1];
        v[2] = t[c][ws_ * 4 + 2]; v[3] = t[c][ws_ * 4 + 3];
        *(ushort4v*)&out[(size_t)(c0 + c) * 2048 + s0 + ws_ * 4] = v;
    }
}

// ---------------- GEMM (m97 structure, 128^2): A bf16 [M][lda], Bt bf16 [N][K] ----------------
__global__ __launch_bounds__(256) void gemm_tn(const unsigned short* __restrict__ A, int lda,
                                               const unsigned short* __restrict__ Bt,
                                               float* __restrict__ Cf,
                                               unsigned short* __restrict__ Cb,
                                               const float* __restrict__ addsrc,
                                               int N, int K) {
    __shared__ unsigned short As[128 * 64];
    __shared__ unsigned short Bs[128 * 64];
    int tid = threadIdx.x;
    int lane = tid & 63;
    int wid = tid >> 6;
    int wrow = wid >> 1, wcol = wid & 1;
    int lr = lane & 15, lg = lane >> 4;
    const int m0 = blockIdx.x * 128, n0 = blockIdx.y * 128;

    const unsigned short* aG = A + (size_t)(m0 + wid * 32 + (lane >> 3)) * lda + (lane & 7) * 8;
    const unsigned short* bG = Bt + (size_t)(n0 + wid * 32 + (lane >> 3)) * K + (lane & 7) * 8;
    unsigned short* aL = As + wid * 2048;
    unsigned short* bL = Bs + wid * 2048;

    f32x4 acc[4][4] = {};

    for (int k0 = 0; k0 < K; k0 += 64) {
#pragma unroll
        for (int i = 0; i < 4; ++i)
            gload16(aG + (size_t)(i * 8) * lda + k0, aL + i * 512);
#pragma unroll
        for (int i = 0; i < 4; ++i)
            gload16(bG + (size_t)(i * 8) * K + k0, bL + i * 512);
        __syncthreads();
#pragma unroll
        for (int kk = 0; kk < 2; ++kk) {
            bf16x8 aF[4], bF[4];
#pragma unroll
            for (int mi = 0; mi < 4; ++mi)
                aF[mi] = *(const bf16x8*)&As[(wrow * 64 + mi * 16 + lr) * 64 + kk * 32 + lg * 8];
#pragma unroll
            for (int ni = 0; ni < 4; ++ni)
                bF[ni] = *(const bf16x8*)&Bs[(wcol * 64 + ni * 16 + lr) * 64 + kk * 32 + lg * 8];
#pragma unroll
            for (int mi = 0; mi < 4; ++mi)
#pragma unroll
                for (int ni = 0; ni < 4; ++ni)
                    acc[mi][ni] = __builtin_amdgcn_mfma_f32_16x16x32_bf16(aF[mi], bF[ni], acc[mi][ni], 0, 0, 0);
        }
        __syncthreads();
    }
#pragma unroll
    for (int mi = 0; mi < 4; ++mi)
#pragma unroll
        for (int ni = 0; ni < 4; ++ni) {
            int row = m0 + wrow * 64 + mi * 16 + lg * 4;
            int col = n0 + wcol * 64 + ni * 16 + lr;
#pragma unroll
            for (int r = 0; r < 4; ++r) {
                size_t idx = (size_t)(row + r) * N + col;
                float v = acc[mi][ni][r];
                if (addsrc) v += addsrc[idx];
                if (Cb) Cb[idx] = f2bf(v);
                else    Cf[idx] = v;
            }
        }
}

// ---------------- GEMM 256^2 8-phase (T2+T3+T4+T5): A bf16 [M][K], Bt bf16 [N][K] ----------------
// 512 threads = 8 waves (2m x 4n). LDS 128 KiB = 2 buf x {A,B} x 2 kslice x [256][32].
// Swizzle: granule g' = g ^ ((row>>1)&3), applied on pre-swizzled global src + ds_read addr.
#define BAR()  asm volatile("s_barrier" ::: "memory")
#define WAITV(n) asm volatile("s_waitcnt vmcnt(" #n ")" ::: "memory")
#define LGKM0() do { asm volatile("s_waitcnt lgkmcnt(0)" ::: "memory"); __builtin_amdgcn_sched_barrier(0); } while (0)

__global__ __launch_bounds__(512) void gemm8(const unsigned short* __restrict__ A,
                                             const unsigned short* __restrict__ Bt,
                                             float* __restrict__ Cf,
                                             unsigned short* __restrict__ Cb,
                                             int N, int K) {
    __shared__ unsigned short ldsbuf[65536];
    const int NT = K >> 6;
    int tid = threadIdx.x;
    int lane = tid & 63;
    int wid = tid >> 6;
    int wm = wid >> 2, wn = wid & 3;
    int lr = lane & 15, lg = lane >> 4;
    const int m0 = blockIdx.x * 256, n0 = blockIdx.y * 256;

    unsigned lds0 = (unsigned)(size_t)(__attribute__((address_space(3))) unsigned short*)ldsbuf;
    const unsigned xoff = (unsigned)((lg ^ ((lr >> 1) & 3)) * 16);
    const int gsw = (lane & 3) ^ ((lane >> 3) & 3);
    const int srow = wid * 16 + (lane >> 2);

    // stage unit: (buf, ab, s) <- K-tile t. 2 x gload16/thread (rows srow, srow+128).
#define STAGE(buf, ab, s, t) do {                                                   \
        const unsigned short* _src = (ab) ? Bt : A;                                 \
        int _r0 = (ab) ? n0 : m0;                                                   \
        unsigned short* _l = ldsbuf + (((buf) * 2 + (ab)) * 2 + (s)) * 8192 + wid * 512; \
        const unsigned short* _g = _src + (size_t)(_r0 + srow) * K + (size_t)(t) * 64 + (s) * 32 + gsw * 8; \
        gload16(_g, _l);                                                            \
        gload16(_g + (size_t)128 * K, _l + 4096);                                   \
    } while (0)

    f32x4 acc[8][4] = {};

    // prologue: tile0 (buf0) fully + tile1 (buf1) slice0
    STAGE(0, 0, 0, 0); STAGE(0, 1, 0, 0);
    STAGE(0, 0, 1, 0); STAGE(0, 1, 1, 0);
    STAGE(1, 0, 0, 1); STAGE(1, 1, 0, 1);
    WAITV(8);
    BAR();

    for (int t = 0; t < NT; ++t) {
        int buf = t & 1;
        unsigned aBase = lds0 + (unsigned)(buf * 65536) + (unsigned)((wm * 128 + lr) * 64) + xoff;
        unsigned bBase = lds0 + (unsigned)(buf * 65536 + 32768) + (unsigned)((wn * 64 + lr) * 64) + xoff;
        Frag aF[4], bF[4];
#pragma unroll
        for (int s = 0; s < 2; ++s) {
            // ---- phase (s, mh=0): read B(s) + A(s, rows mh0) ----
#pragma unroll
            for (int ni = 0; ni < 4; ++ni)
                bF[ni].f = lds_read_b128(bBase + (unsigned)(s * 16384 + ni * 1024));
#pragma unroll
            for (int mi = 0; mi < 4; ++mi)
                aF[mi].f = lds_read_b128(aBase + (unsigned)(s * 16384 + mi * 1024));
            if (s == 0) { if (t + 1 < NT) STAGE(buf ^ 1, 0, 1, t + 1); }
            else        { if (t + 2 < NT) STAGE(buf,     0, 0, t + 2); }
            BAR();
            LGKM0();
            __builtin_amdgcn_s_setprio(1);
#pragma unroll
            for (int mi = 0; mi < 4; ++mi)
#pragma unroll
                for (int ni = 0; ni < 4; ++ni)
                    acc[mi][ni] = __builtin_amdgcn_mfma_f32_16x16x32_bf16(aF[mi].h, bF[ni].h, acc[mi][ni], 0, 0, 0);
            __builtin_amdgcn_s_setprio(0);
            BAR();
            // ---- phase (s, mh=1): read A(s, rows mh1); B kept in regs ----
#pragma unroll
            for (int mi = 0; mi < 4; ++mi)
                aF[mi].f = lds_read_b128(aBase + (unsigned)(4096 + s * 16384 + mi * 1024));
            if (s == 0) { if (t + 1 < NT) STAGE(buf ^ 1, 1, 1, t + 1); }
            else        { if (t + 2 < NT) STAGE(buf,     1, 0, t + 2); }
            BAR();
            LGKM0();
            __builtin_amdgcn_s_setprio(1);
#pragma unroll
            for (int mi = 0; mi < 4; ++mi)
#pragma unroll
                for (int ni = 0; ni < 4; ++ni)
                    acc[4 + mi][ni] = __builtin_amdgcn_mfma_f32_16x16x32_bf16(aF[mi].h, bF[ni].h, acc[4 + mi][ni], 0, 0, 0);
            __builtin_amdgcn_s_setprio(0);
            if (s == 0) {
                if (t + 1 < NT) { WAITV(8); } else { WAITV(0); }
            } else {
                if (t + 2 < NT)      { WAITV(8); }
                else if (t + 1 < NT) { WAITV(4); }
            }
            BAR();
        }
    }
#undef STAGE

#pragma unroll
    for (int mi = 0; mi < 8; ++mi)
#pragma unroll
        for (int ni = 0; ni < 4; ++ni) {
            int row = m0 + wm * 128 + mi * 16 + lg * 4;
            int col = n0 + wn * 64 + ni * 16 + lr;
#pragma unroll
            for (int r = 0; r < 4; ++r) {
                size_t idx = (size_t)(row + r) * N + col;
                float v = acc[mi][ni][r];
                if (Cb) Cb[idx] = f2bf(v);
                else    Cf[idx] = v;
            }
        }
}

// ---------------- RoPE on fused qkv f32 [S][2048]; writes bf16 qb/kb/vb + news ----------------
__global__ __launch_bounds__(64) void rope_kernel(const float* __restrict__ qkv,
                                                  const float* __restrict__ fc,
                                                  const float* __restrict__ fs,
                                                  unsigned short* __restrict__ qb,
                                                  unsigned short* __restrict__ kb,
                                                  unsigned short* __restrict__ vb,
                                                  float* __restrict__ out, int layer) {
    const size_t LOGITS = (size_t)S_LEN * 32000;
    int s = blockIdx.x;
    int hh = blockIdx.y;
    int lane = threadIdx.x;
    const float* base = qkv + (size_t)s * 2048;
    if (hh < NH) {
        if (lane < 32) {
            const float* row = base + hh * HD;
            float xr = row[2 * lane], xi = row[2 * lane + 1];
            float c = fc[s * 32 + lane], sn = fs[s * 32 + lane];
            size_t o = (size_t)s * (NH * HD) + hh * HD + lane;
            qb[o] = f2bf(xr * c - xi * sn);
            qb[o + 32] = f2bf(xr * sn + xi * c);
        }
    } else if (hh < NH + NKV) {
        int kh = hh - NH;
        if (lane < 32) {
            const float* row = base + 1024 + kh * HD;
            float xr = row[2 * lane], xi = row[2 * lane + 1];
            float c = fc[s * 32 + lane], sn = fs[s * 32 + lane];
            float o0 = xr * c - xi * sn, o1 = xr * sn + xi * c;
            size_t o = (size_t)s * (NKV * HD) + kh * HD + lane;
            kb[o] = f2bf(o0);
            kb[o + 32] = f2bf(o1);
            if (s == S_LEN - 1) {
                float* kn = out + LOGITS + (size_t)layer * (NKV * HD) + kh * HD;
                kn[lane] = o0; kn[lane + 32] = o1;
            }
        }
    } else {
        int vh = hh - NH - NKV;
        const float* row = base + 1536 + vh * HD;
        float val = row[lane];
        vb[(size_t)s * (NKV * HD) + vh * HD + lane] = f2bf(val);
        if (s == S_LEN - 1)
            out[LOGITS + (size_t)2 * (NKV * HD) + (size_t)layer * (NKV * HD) + vh * HD + lane] = val;
    }
}

// ---------------- flash attention: 1 wave per (16 q rows, head); KVBLK=64, V transposed ----------------
__global__ __launch_bounds__(64) void attn_kernel(const unsigned short* __restrict__ qb,
                                                  const unsigned short* __restrict__ kb,
                                                  const unsigned short* __restrict__ vT,
                                                  unsigned short* __restrict__ yb) {
    int qt = blockIdx.x;     // 0..127
    int h = blockIdx.y;      // 0..15
    int kvh = h >> 1;        // rep = 2
    int lane = threadIdx.x;
    int lr = lane & 15, lg = lane >> 4;

    __shared__ unsigned short P[16 * 72];

    bf16x8 aq[2];
    int qrow = qt * 16 + lr;
#pragma unroll
    for (int c = 0; c < 2; ++c)
        aq[c] = *(const bf16x8*)&qb[(size_t)qrow * (NH * HD) + h * HD + c * 32 + lg * 8];

    f32x4 O[4] = {};
    float m[4], l[4];
#pragma unroll
    for (int r = 0; r < 4; ++r) { m[r] = -1e30f; l[r] = 0.f; }

    int ktiles = (qt * 16 + 15) / 64 + 1;
    for (int kt = 0; kt < ktiles; ++kt) {
        f32x4 s[4];
#pragma unroll
        for (int kc = 0; kc < 4; ++kc) {
            int key = kt * 64 + kc * 16 + lr;
            const unsigned short* krow = &kb[(size_t)key * (NKV * HD) + kvh * HD];
            bf16x8 bk0 = *(const bf16x8*)&krow[lg * 8];
            bf16x8 bk1 = *(const bf16x8*)&krow[32 + lg * 8];
            f32x4 z = {};
            z = __builtin_amdgcn_mfma_f32_16x16x32_bf16(aq[0], bk0, z, 0, 0, 0);
            z = __builtin_amdgcn_mfma_f32_16x16x32_bf16(aq[1], bk1, z, 0, 0, 0);
            s[kc] = z;
        }
        float pv[4][4];
#pragma unroll
        for (int r = 0; r < 4; ++r) {
            int row = qt * 16 + lg * 4 + r;
            float tm = -1e30f;
#pragma unroll
            for (int kc = 0; kc < 4; ++kc) {
                int key = kt * 64 + kc * 16 + lr;
                float val = s[kc][r] * 0.125f;
                if (key > row) val = -1e30f;
                pv[kc][r] = val;
                tm = fmaxf(tm, val);
            }
#pragma unroll
            for (int off = 1; off < 16; off <<= 1)
                tm = fmaxf(tm, __shfl_xor(tm, off));
            float mn = fmaxf(m[r], tm);
            float sc = __expf(m[r] - mn);
            l[r] *= sc;
#pragma unroll
            for (int n = 0; n < 4; ++n) O[n][r] *= sc;
            float rs = 0.f;
#pragma unroll
            for (int kc = 0; kc < 4; ++kc) {
                float p = __expf(pv[kc][r] - mn);
                pv[kc][r] = p;
                rs += p;
            }
#pragma unroll
            for (int off = 1; off < 16; off <<= 1)
                rs += __shfl_xor(rs, off);
            l[r] += rs;
            m[r] = mn;
        }
#pragma unroll
        for (int r = 0; r < 4; ++r)
#pragma unroll
            for (int kc = 0; kc < 4; ++kc)
                P[(lg * 4 + r) * 72 + kc * 16 + lr] = f2bf(pv[kc][r]);
        __syncthreads();
        bf16x8 pa[2];
#pragma unroll
        for (int g = 0; g < 2; ++g)
            pa[g] = *(const bf16x8*)&P[lr * 72 + g * 32 + lg * 8];
#pragma unroll
        for (int n = 0; n < 4; ++n) {
#pragma unroll
            for (int g = 0; g < 2; ++g) {
                bf16x8 bv = *(const bf16x8*)&vT[(size_t)(kvh * 64 + n * 16 + lr) * 2048 + kt * 64 + g * 32 + lg * 8];
                O[n] = __builtin_amdgcn_mfma_f32_16x16x32_bf16(pa[g], bv, O[n], 0, 0, 0);
            }
        }
        __syncthreads();
    }
#pragma unroll
    for (int n = 0; n < 4; ++n)
#pragma unroll
        for (int r = 0; r < 4; ++r) {
            int row = qt * 16 + lg * 4 + r;
            yb[(size_t)row * (NH * HD) + h * HD + n * 16 + lr] = f2bf(O[n][r] / l[r]);
        }
}

// ---------------- silu(g)*u in fused gu bf16 [S][5632], in place into g half ----------------
__global__ __launch_bounds__(256) void silu_mul_kernel(unsigned short* __restrict__ gu) {
    size_t idx = (size_t)blockIdx.x * 256 + threadIdx.x;
    int s = (int)(idx / 352);
    int c8 = (int)(idx % 352);
    unsigned short* gp = gu + (size_t)s * 5632 + c8 * 8;
    ushort8v a = *(const ushort8v*)gp;
    ushort8v b = *(const ushort8v*)(gp + 2816);
#pragma unroll
    for (int j = 0; j < 8; ++j) {
        float x = bf2f(a[j]), y = bf2f(b[j]);
        a[j] = f2bf(x / (1.f + __expf(-x)) * y);
    }
    *(ushort8v*)gp = a;
}

extern "C" void kernel_launch(void* const* d_in, const int* in_sizes, int n_in,
                              void* d_out, int out_size, void* d_ws, size_t ws_size,
                              hipStream_t stream) {
    const int* tokens = (const int*)d_in[0];
    const float* freqs_cos = (const float*)d_in[2];
    const float* freqs_sin = (const float*)d_in[3];
    const float* tok_emb = (const float*)d_in[4];
    const float* wq = (const float*)d_in[5];
    const float* wk = (const float*)d_in[6];
    const float* wv = (const float*)d_in[7];
    const float* wo = (const float*)d_in[8];
    const float* attn_norm_w = (const float*)d_in[9];
    const float* ffn_norm_w = (const float*)d_in[10];
    const float* w1 = (const float*)d_in[11];
    const float* w2 = (const float*)d_in[12];
    const float* w3 = (const float*)d_in[13];
    const float* final_norm_w = (const float*)d_in[14];
    const float* out_w = (const float*)d_in[15];
    float* out = (float*)d_out;

    const size_t SD = (size_t)S_LEN * DIM;
    const size_t SKV = (size_t)S_LEN * NKV * HD;

    char* p = (char*)d_ws;
    auto take = [&](size_t bytes) { char* r = p; p += (bytes + 255) & ~(size_t)255; return r; };
    float* h            = (float*)take(SD * 4);
    unsigned short* xnb = (unsigned short*)take(SD * 2);
    char* uni = p;
    float* qkvf         = (float*)uni;                                  // 16 MB
    unsigned short* qb  = (unsigned short*)(uni + 17039360);            // 4 MB
    unsigned short* kb  = qb + SD;                                      // 2 MB
    unsigned short* vb  = kb + SKV;                                     // 2 MB
    unsigned short* vT  = vb + SKV;                                     // 2 MB
    unsigned short* ybv = vT + SKV;                                     // 4 MB
    unsigned short* gu  = ybv + SD;                                     // 23 MB
    unsigned short* wT  = gu + (size_t)S_LEN * 5632;                    // 11.5 MB
    unsigned short* owT = (unsigned short*)uni;                         // 65.5 MB (final phase)

    embed_kernel<<<S_LEN, 256, 0, stream>>>(tokens, tok_emb, h);
    for (int l = 0; l < 2; ++l) {
        rmsnorm_kernel<<<S_LEN, 256, 0, stream>>>(h, attn_norm_w + l * DIM, xnb);
        transpose_w<<<dim3(16, 16), 256, 0, stream>>>(wq + (size_t)l * DIM * 1024, wT, DIM, 1024);
        transpose_w<<<dim3(8, 16), 256, 0, stream>>>(wk + (size_t)l * DIM * 512, wT + (size_t)1024 * DIM, DIM, 512);
        transpose_w<<<dim3(8, 16), 256, 0, stream>>>(wv + (size_t)l * DIM * 512, wT + (size_t)1536 * DIM, DIM, 512);
        gemm_tn<<<dim3(16, 16), 256, 0, stream>>>(xnb, DIM, wT, qkvf, nullptr, nullptr, 2048, DIM);
        rope_kernel<<<dim3(S_LEN, 32), 64, 0, stream>>>(qkvf, freqs_cos, freqs_sin, qb, kb, vb, out, l);
        transpose_v<<<dim3(8, 32), 256, 0, stream>>>(vb, vT);
        attn_kernel<<<dim3(S_LEN / 16, NH), 64, 0, stream>>>(qb, kb, vT, ybv);
        transpose_w<<<dim3(16, 16), 256, 0, stream>>>(wo + (size_t)l * 1024 * DIM, wT, 1024, DIM);
        gemm_tn<<<dim3(16, 8), 256, 0, stream>>>(ybv, 1024, wT, h, nullptr, h, DIM, 1024);
        rmsnorm_kernel<<<S_LEN, 256, 0, stream>>>(h, ffn_norm_w + l * DIM, xnb);
        transpose_w<<<dim3(44, 16), 256, 0, stream>>>(w1 + (size_t)l * DIM * HID, wT, DIM, HID);
        transpose_w<<<dim3(44, 16), 256, 0, stream>>>(w3 + (size_t)l * DIM * HID, wT + (size_t)HID * DIM, DIM, HID);
        gemm8<<<dim3(8, 22), 512, 0, stream>>>(xnb, wT, nullptr, gu, 5632, DIM);
        silu_mul_kernel<<<(S_LEN * 352) / 256, 256, 0, stream>>>(gu);
        transpose_w<<<dim3(16, 44), 256, 0, stream>>>(w2 + (size_t)l * HID * 1024, wT, HID, 1024);
        gemm_tn<<<dim3(16, 8), 256, 0, stream>>>(gu, 5632, wT, h, nullptr, h, DIM, HID);
    }
    rmsnorm_kernel<<<S_LEN, 256, 0, stream>>>(h, final_norm_w, xnb);
    transpose_w<<<dim3(500, 16), 256, 0, stream>>>(out_w, owT, DIM, 32000);
    gemm8<<<dim3(8, 125), 512, 0, stream>>>(xnb, owT, out, nullptr, 32000, DIM);
}

// Round 4
// 955.586 us; speedup vs baseline: 1.6120x; 1.0005x over previous
//
#include <hip/hip_runtime.h>
#include <hip/hip_bf16.h>

typedef __bf16 bf16x8 __attribute__((ext_vector_type(8)));
typedef float f32x4 __attribute__((ext_vector_type(4)));
typedef unsigned short ushort4v __attribute__((ext_vector_type(4)));
typedef unsigned short ushort8v __attribute__((ext_vector_type(8)));

#define S_LEN 2048
#define DIM 1024
#define NH 16
#define NKV 8
#define HD 64
#define HID 2816

__device__ __forceinline__ unsigned short f2bf(float f) {
    union { float f; unsigned u; } v; v.f = f;
    unsigned r = v.u + 0x7fffu + ((v.u >> 16) & 1u);   // RNE
    return (unsigned short)(r >> 16);
}
__device__ __forceinline__ float bf2f(unsigned short u) {
    union { unsigned u; float f; } v; v.u = (unsigned)u << 16; return v.f;
}

__device__ __forceinline__ void gload16(const unsigned short* g, unsigned short* l) {
    __builtin_amdgcn_global_load_lds(
        (const __attribute__((address_space(1))) unsigned int*)g,
        (__attribute__((address_space(3))) unsigned int*)l,
        16, 0, 0);
}

union Frag { f32x4 f; bf16x8 h; };

__device__ __forceinline__ f32x4 lds_read_b128(unsigned addr) {
    f32x4 d;
    asm volatile("ds_read_b128 %0, %1" : "=v"(d) : "v"(addr));
    return d;
}

// ---------------- embedding gather ----------------
__global__ __launch_bounds__(256) void embed_kernel(const int* __restrict__ tokens,
                                                    const float* __restrict__ emb,
                                                    float* __restrict__ h) {
    int s = blockIdx.x;
    int t = tokens[s];
    float4 v = *(const float4*)&emb[(size_t)t * DIM + threadIdx.x * 4];
    *(float4*)&h[(size_t)s * DIM + threadIdx.x * 4] = v;
}

// ---------------- rmsnorm: f32 in -> bf16 out ----------------
__global__ __launch_bounds__(256) void rmsnorm_kernel(const float* __restrict__ x,
                                                      const float* __restrict__ w,
                                                      unsigned short* __restrict__ out) {
    __shared__ float sred[4];
    int s = blockIdx.x;
    int tid = threadIdx.x;
    float4 v = *(const float4*)&x[(size_t)s * DIM + tid * 4];
    float ss = v.x * v.x + v.y * v.y + v.z * v.z + v.w * v.w;
#pragma unroll
    for (int off = 32; off; off >>= 1) ss += __shfl_down(ss, off);
    if ((tid & 63) == 0) sred[tid >> 6] = ss;
    __syncthreads();
    float tot = sred[0] + sred[1] + sred[2] + sred[3];
    float scale = rsqrtf(tot * (1.0f / DIM) + 1e-5f);
    float4 wv = *(const float4*)&w[tid * 4];
    ushort4v o;
    o[0] = f2bf(v.x * scale * wv.x); o[1] = f2bf(v.y * scale * wv.y);
    o[2] = f2bf(v.z * scale * wv.z); o[3] = f2bf(v.w * scale * wv.w);
    *(ushort4v*)&out[(size_t)s * DIM + tid * 4] = o;
}

// ---------------- transpose + convert: f32 [K][N] -> bf16 [N][K] ----------------
__global__ __launch_bounds__(256) void transpose_w(const float* __restrict__ in,
                                                   unsigned short* __restrict__ out,
                                                   int K, int N) {
    __shared__ unsigned short t[64][68];
    int n0 = blockIdx.x * 64, k0 = blockIdx.y * 64;
    int tid = threadIdx.x;
    int tn = tid & 15, tk = tid >> 4;
#pragma unroll
    for (int p = 0; p < 4; ++p) {
        int k = tk + p * 16;
        float4 v = *(const float4*)&in[(size_t)(k0 + k) * N + n0 + tn * 4];
        t[tn * 4 + 0][k] = f2bf(v.x);
        t[tn * 4 + 1][k] = f2bf(v.y);
        t[tn * 4 + 2][k] = f2bf(v.z);
        t[tn * 4 + 3][k] = f2bf(v.w);
    }
    __syncthreads();
    int wk = tid & 15, wn = tid >> 4;
#pragma unroll
    for (int p = 0; p < 4; ++p) {
        int n = wn + p * 16;
        ushort4v v;
        v[0] = t[n][wk * 4]; v[1] = t[n][wk * 4 + 1];
        v[2] = t[n][wk * 4 + 2]; v[3] = t[n][wk * 4 + 3];
        *(ushort4v*)&out[(size_t)(n0 + n) * K + k0 + wk * 4] = v;
    }
}

// ---------------- bf16 transpose: [2048][512] -> [512][2048] (for V) ----------------
__global__ __launch_bounds__(256) void transpose_v(const unsigned short* __restrict__ in,
                                                   unsigned short* __restrict__ out) {
    __shared__ unsigned short t[64][72];
    int c0 = blockIdx.x * 64, s0 = blockIdx.y * 64;
    int tid = threadIdx.x;
    int tc = tid & 15, ts = tid >> 4;
#pragma unroll
    for (int p = 0; p < 4; ++p) {
        int s = ts + p * 16;
        ushort4v v = *(const ushort4v*)&in[(size_t)(s0 + s) * 512 + c0 + tc * 4];
        t[tc * 4 + 0][s] = v[0];
        t[tc * 4 + 1][s] = v[1];
        t[tc * 4 + 2][s] = v[2];
        t[tc * 4 + 3][s] = v[3];
    }
    __syncthreads();
    int ws_ = tid & 15, wc = tid >> 4;
#pragma unroll
    for (int p = 0; p < 4; ++p) {
        int c = wc + p * 16;
        ushort4v v;
        v[0] = t[c][ws_ * 4]; v[1] = t[c][ws_ * 4 + 1];
        v[2] = t[c][ws_ * 4 + 2]; v[3] = t[c][ws_ * 4 + 3];
        *(ushort4v*)&out[(size_t)(c0 + c) * 2048 + s0 + ws_ * 4] = v;
    }
}

// ---------------- GEMM (m97 structure, 128^2): A bf16 [M][lda], Bt bf16 [N][K] ----------------
__global__ __launch_bounds__(256) void gemm_tn(const unsigned short* __restrict__ A, int lda,
                                               const unsigned short* __restrict__ Bt,
                                               float* __restrict__ Cf,
                                               unsigned short* __restrict__ Cb,
                                               const float* __restrict__ addsrc,
                                               int N, int K) {
    __shared__ unsigned short As[128 * 64];
    __shared__ unsigned short Bs[128 * 64];
    int tid = threadIdx.x;
    int lane = tid & 63;
    int wid = tid >> 6;
    int wrow = wid >> 1, wcol = wid & 1;
    int lr = lane & 15, lg = lane >> 4;
    const int m0 = blockIdx.x * 128, n0 = blockIdx.y * 128;

    const unsigned short* aG = A + (size_t)(m0 + wid * 32 + (lane >> 3)) * lda + (lane & 7) * 8;
    const unsigned short* bG = Bt + (size_t)(n0 + wid * 32 + (lane >> 3)) * K + (lane & 7) * 8;
    unsigned short* aL = As + wid * 2048;
    unsigned short* bL = Bs + wid * 2048;

    f32x4 acc[4][4] = {};

    for (int k0 = 0; k0 < K; k0 += 64) {
#pragma unroll
        for (int i = 0; i < 4; ++i)
            gload16(aG + (size_t)(i * 8) * lda + k0, aL + i * 512);
#pragma unroll
        for (int i = 0; i < 4; ++i)
            gload16(bG + (size_t)(i * 8) * K + k0, bL + i * 512);
        __syncthreads();
#pragma unroll
        for (int kk = 0; kk < 2; ++kk) {
            bf16x8 aF[4], bF[4];
#pragma unroll
            for (int mi = 0; mi < 4; ++mi)
                aF[mi] = *(const bf16x8*)&As[(wrow * 64 + mi * 16 + lr) * 64 + kk * 32 + lg * 8];
#pragma unroll
            for (int ni = 0; ni < 4; ++ni)
                bF[ni] = *(const bf16x8*)&Bs[(wcol * 64 + ni * 16 + lr) * 64 + kk * 32 + lg * 8];
#pragma unroll
            for (int mi = 0; mi < 4; ++mi)
#pragma unroll
                for (int ni = 0; ni < 4; ++ni)
                    acc[mi][ni] = __builtin_amdgcn_mfma_f32_16x16x32_bf16(aF[mi], bF[ni], acc[mi][ni], 0, 0, 0);
        }
        __syncthreads();
    }
#pragma unroll
    for (int mi = 0; mi < 4; ++mi)
#pragma unroll
        for (int ni = 0; ni < 4; ++ni) {
            int row = m0 + wrow * 64 + mi * 16 + lg * 4;
            int col = n0 + wcol * 64 + ni * 16 + lr;
#pragma unroll
            for (int r = 0; r < 4; ++r) {
                size_t idx = (size_t)(row + r) * N + col;
                float v = acc[mi][ni][r];
                if (addsrc) v += addsrc[idx];
                if (Cb) Cb[idx] = f2bf(v);
                else    Cf[idx] = v;
            }
        }
}

// ---------------- GEMM 256^2 8-phase (T2+T3+T4+T5): A bf16 [M][K], Bt bf16 [N][K] ----------------
// 512 threads = 8 waves (2m x 4n). LDS 128 KiB = 2 buf x {A,B} x 2 kslice x [256][32].
// Swizzle: granule g' = g ^ ((row>>1)&3), applied on pre-swizzled global src + ds_read addr.
#define BAR()  asm volatile("s_barrier" ::: "memory")
#define WAITV(n) asm volatile("s_waitcnt vmcnt(" #n ")" ::: "memory")
#define LGKM0() do { asm volatile("s_waitcnt lgkmcnt(0)" ::: "memory"); __builtin_amdgcn_sched_barrier(0); } while (0)

__global__ __launch_bounds__(512) void gemm8(const unsigned short* __restrict__ A,
                                             const unsigned short* __restrict__ Bt,
                                             float* __restrict__ Cf,
                                             unsigned short* __restrict__ Cb,
                                             int N, int K) {
    __shared__ unsigned short ldsbuf[65536];
    const int NT = K >> 6;
    int tid = threadIdx.x;
    int lane = tid & 63;
    int wid = tid >> 6;
    int wm = wid >> 2, wn = wid & 3;
    int lr = lane & 15, lg = lane >> 4;
    const int m0 = blockIdx.x * 256, n0 = blockIdx.y * 256;

    unsigned lds0 = (unsigned)(size_t)(__attribute__((address_space(3))) unsigned short*)ldsbuf;
    const unsigned xoff = (unsigned)((lg ^ ((lr >> 1) & 3)) * 16);
    const int gsw = (lane & 3) ^ ((lane >> 3) & 3);
    const int srow = wid * 16 + (lane >> 2);

    // stage unit: (buf, ab, s) <- K-tile t. 2 x gload16/thread (rows srow, srow+128).
#define STAGE(buf, ab, s, t) do {                                                   \
        const unsigned short* _src = (ab) ? Bt : A;                                 \
        int _r0 = (ab) ? n0 : m0;                                                   \
        unsigned short* _l = ldsbuf + (((buf) * 2 + (ab)) * 2 + (s)) * 8192 + wid * 512; \
        const unsigned short* _g = _src + (size_t)(_r0 + srow) * K + (size_t)(t) * 64 + (s) * 32 + gsw * 8; \
        gload16(_g, _l);                                                            \
        gload16(_g + (size_t)128 * K, _l + 4096);                                   \
    } while (0)

    f32x4 acc[8][4] = {};

    // prologue: tile0 (buf0) fully + tile1 (buf1) slice0
    STAGE(0, 0, 0, 0); STAGE(0, 1, 0, 0);
    STAGE(0, 0, 1, 0); STAGE(0, 1, 1, 0);
    STAGE(1, 0, 0, 1); STAGE(1, 1, 0, 1);
    WAITV(8);
    BAR();

    for (int t = 0; t < NT; ++t) {
        int buf = t & 1;
        unsigned aBase = lds0 + (unsigned)(buf * 65536) + (unsigned)((wm * 128 + lr) * 64) + xoff;
        unsigned bBase = lds0 + (unsigned)(buf * 65536 + 32768) + (unsigned)((wn * 64 + lr) * 64) + xoff;
        Frag aF[4], bF[4];
#pragma unroll
        for (int s = 0; s < 2; ++s) {
            // ---- phase (s, mh=0): read B(s) + A(s, rows mh0) ----
#pragma unroll
            for (int ni = 0; ni < 4; ++ni)
                bF[ni].f = lds_read_b128(bBase + (unsigned)(s * 16384 + ni * 1024));
#pragma unroll
            for (int mi = 0; mi < 4; ++mi)
                aF[mi].f = lds_read_b128(aBase + (unsigned)(s * 16384 + mi * 1024));
            if (s == 0) { if (t + 1 < NT) STAGE(buf ^ 1, 0, 1, t + 1); }
            else        { if (t + 2 < NT) STAGE(buf,     0, 0, t + 2); }
            BAR();
            LGKM0();
            __builtin_amdgcn_s_setprio(1);
#pragma unroll
            for (int mi = 0; mi < 4; ++mi)
#pragma unroll
                for (int ni = 0; ni < 4; ++ni)
                    acc[mi][ni] = __builtin_amdgcn_mfma_f32_16x16x32_bf16(aF[mi].h, bF[ni].h, acc[mi][ni], 0, 0, 0);
            __builtin_amdgcn_s_setprio(0);
            BAR();
            // ---- phase (s, mh=1): read A(s, rows mh1); B kept in regs ----
#pragma unroll
            for (int mi = 0; mi < 4; ++mi)
                aF[mi].f = lds_read_b128(aBase + (unsigned)(4096 + s * 16384 + mi * 1024));
            if (s == 0) { if (t + 1 < NT) STAGE(buf ^ 1, 1, 1, t + 1); }
            else        { if (t + 2 < NT) STAGE(buf,     1, 0, t + 2); }
            BAR();
            LGKM0();
            __builtin_amdgcn_s_setprio(1);
#pragma unroll
            for (int mi = 0; mi < 4; ++mi)
#pragma unroll
                for (int ni = 0; ni < 4; ++ni)
                    acc[4 + mi][ni] = __builtin_amdgcn_mfma_f32_16x16x32_bf16(aF[mi].h, bF[ni].h, acc[4 + mi][ni], 0, 0, 0);
            __builtin_amdgcn_s_setprio(0);
            if (s == 0) {
                if (t + 1 < NT) { WAITV(8); } else { WAITV(0); }
            } else {
                if (t + 2 < NT)      { WAITV(8); }
                else if (t + 1 < NT) { WAITV(4); }
            }
            BAR();
        }
    }
#undef STAGE

#pragma unroll
    for (int mi = 0; mi < 8; ++mi)
#pragma unroll
        for (int ni = 0; ni < 4; ++ni) {
            int row = m0 + wm * 128 + mi * 16 + lg * 4;
            int col = n0 + wn * 64 + ni * 16 + lr;
#pragma unroll
            for (int r = 0; r < 4; ++r) {
                size_t idx = (size_t)(row + r) * N + col;
                float v = acc[mi][ni][r];
                if (Cb) Cb[idx] = f2bf(v);
                else    Cf[idx] = v;
            }
        }
}

// ---------------- RoPE on fused qkv f32 [S][2048]; writes bf16 qb/kb/vb + news ----------------
__global__ __launch_bounds__(64) void rope_kernel(const float* __restrict__ qkv,
                                                  const float* __restrict__ fc,
                                                  const float* __restrict__ fs,
                                                  unsigned short* __restrict__ qb,
                                                  unsigned short* __restrict__ kb,
                                                  unsigned short* __restrict__ vb,
                                                  float* __restrict__ out, int layer) {
    const size_t LOGITS = (size_t)S_LEN * 32000;
    int s = blockIdx.x;
    int hh = blockIdx.y;
    int lane = threadIdx.x;
    const float* base = qkv + (size_t)s * 2048;
    if (hh < NH) {
        if (lane < 32) {
            const float* row = base + hh * HD;
            float xr = row[2 * lane], xi = row[2 * lane + 1];
            float c = fc[s * 32 + lane], sn = fs[s * 32 + lane];
            size_t o = (size_t)s * (NH * HD) + hh * HD + lane;
            qb[o] = f2bf(xr * c - xi * sn);
            qb[o + 32] = f2bf(xr * sn + xi * c);
        }
    } else if (hh < NH + NKV) {
        int kh = hh - NH;
        if (lane < 32) {
            const float* row = base + 1024 + kh * HD;
            float xr = row[2 * lane], xi = row[2 * lane + 1];
            float c = fc[s * 32 + lane], sn = fs[s * 32 + lane];
            float o0 = xr * c - xi * sn, o1 = xr * sn + xi * c;
            size_t o = (size_t)s * (NKV * HD) + kh * HD + lane;
            kb[o] = f2bf(o0);
            kb[o + 32] = f2bf(o1);
            if (s == S_LEN - 1) {
                float* kn = out + LOGITS + (size_t)layer * (NKV * HD) + kh * HD;
                kn[lane] = o0; kn[lane + 32] = o1;
            }
        }
    } else {
        int vh = hh - NH - NKV;
        const float* row = base + 1536 + vh * HD;
        float val = row[lane];
        vb[(size_t)s * (NKV * HD) + vh * HD + lane] = f2bf(val);
        if (s == S_LEN - 1)
            out[LOGITS + (size_t)2 * (NKV * HD) + (size_t)layer * (NKV * HD) + vh * HD + lane] = val;
    }
}

// ---------------- flash attention: 1 wave per (16 q rows, head); KVBLK=64, V transposed ----------------
__global__ __launch_bounds__(64) void attn_kernel(const unsigned short* __restrict__ qb,
                                                  const unsigned short* __restrict__ kb,
                                                  const unsigned short* __restrict__ vT,
                                                  unsigned short* __restrict__ yb) {
    int qt = blockIdx.x;     // 0..127
    int h = blockIdx.y;      // 0..15
    int kvh = h >> 1;        // rep = 2
    int lane = threadIdx.x;
    int lr = lane & 15, lg = lane >> 4;

    __shared__ unsigned short P[16 * 72];

    bf16x8 aq[2];
    int qrow = qt * 16 + lr;
#pragma unroll
    for (int c = 0; c < 2; ++c)
        aq[c] = *(const bf16x8*)&qb[(size_t)qrow * (NH * HD) + h * HD + c * 32 + lg * 8];

    f32x4 O[4] = {};
    float m[4], l[4];
#pragma unroll
    for (int r = 0; r < 4; ++r) { m[r] = -1e30f; l[r] = 0.f; }

    int ktiles = (qt * 16 + 15) / 64 + 1;
    for (int kt = 0; kt < ktiles; ++kt) {
        f32x4 s[4];
#pragma unroll
        for (int kc = 0; kc < 4; ++kc) {
            int key = kt * 64 + kc * 16 + lr;
            const unsigned short* krow = &kb[(size_t)key * (NKV * HD) + kvh * HD];
            bf16x8 bk0 = *(const bf16x8*)&krow[lg * 8];
            bf16x8 bk1 = *(const bf16x8*)&krow[32 + lg * 8];
            f32x4 z = {};
            z = __builtin_amdgcn_mfma_f32_16x16x32_bf16(aq[0], bk0, z, 0, 0, 0);
            z = __builtin_amdgcn_mfma_f32_16x16x32_bf16(aq[1], bk1, z, 0, 0, 0);
            s[kc] = z;
        }
        float pv[4][4];
#pragma unroll
        for (int r = 0; r < 4; ++r) {
            int row = qt * 16 + lg * 4 + r;
            float tm = -1e30f;
#pragma unroll
            for (int kc = 0; kc < 4; ++kc) {
                int key = kt * 64 + kc * 16 + lr;
                float val = s[kc][r] * 0.125f;
                if (key > row) val = -1e30f;
                pv[kc][r] = val;
                tm = fmaxf(tm, val);
            }
#pragma unroll
            for (int off = 1; off < 16; off <<= 1)
                tm = fmaxf(tm, __shfl_xor(tm, off));
            float mn = fmaxf(m[r], tm);
            float sc = __expf(m[r] - mn);
            l[r] *= sc;
#pragma unroll
            for (int n = 0; n < 4; ++n) O[n][r] *= sc;
            float rs = 0.f;
#pragma unroll
            for (int kc = 0; kc < 4; ++kc) {
                float p = __expf(pv[kc][r] - mn);
                pv[kc][r] = p;
                rs += p;
            }
#pragma unroll
            for (int off = 1; off < 16; off <<= 1)
                rs += __shfl_xor(rs, off);
            l[r] += rs;
            m[r] = mn;
        }
#pragma unroll
        for (int r = 0; r < 4; ++r)
#pragma unroll
            for (int kc = 0; kc < 4; ++kc)
                P[(lg * 4 + r) * 72 + kc * 16 + lr] = f2bf(pv[kc][r]);
        __syncthreads();
        bf16x8 pa[2];
#pragma unroll
        for (int g = 0; g < 2; ++g)
            pa[g] = *(const bf16x8*)&P[lr * 72 + g * 32 + lg * 8];
#pragma unroll
        for (int n = 0; n < 4; ++n) {
#pragma unroll
            for (int g = 0; g < 2; ++g) {
                bf16x8 bv = *(const bf16x8*)&vT[(size_t)(kvh * 64 + n * 16 + lr) * 2048 + kt * 64 + g * 32 + lg * 8];
                O[n] = __builtin_amdgcn_mfma_f32_16x16x32_bf16(pa[g], bv, O[n], 0, 0, 0);
            }
        }
        __syncthreads();
    }
#pragma unroll
    for (int n = 0; n < 4; ++n)
#pragma unroll
        for (int r = 0; r < 4; ++r) {
            int row = qt * 16 + lg * 4 + r;
            yb[(size_t)row * (NH * HD) + h * HD + n * 16 + lr] = f2bf(O[n][r] / l[r]);
        }
}

// ---------------- silu(g)*u in fused gu bf16 [S][5632], in place into g half ----------------
__global__ __launch_bounds__(256) void silu_mul_kernel(unsigned short* __restrict__ gu) {
    size_t idx = (size_t)blockIdx.x * 256 + threadIdx.x;
    int s = (int)(idx / 352);
    int c8 = (int)(idx % 352);
    unsigned short* gp = gu + (size_t)s * 5632 + c8 * 8;
    ushort8v a = *(const ushort8v*)gp;
    ushort8v b = *(const ushort8v*)(gp + 2816);
#pragma unroll
    for (int j = 0; j < 8; ++j) {
        float x = bf2f(a[j]), y = bf2f(b[j]);
        a[j] = f2bf(x / (1.f + __expf(-x)) * y);
    }
    *(ushort8v*)gp = a;
}

extern "C" void kernel_launch(void* const* d_in, const int* in_sizes, int n_in,
                              void* d_out, int out_size, void* d_ws, size_t ws_size,
                              hipStream_t stream) {
    const int* tokens = (const int*)d_in[0];
    const float* freqs_cos = (const float*)d_in[2];
    const float* freqs_sin = (const float*)d_in[3];
    const float* tok_emb = (const float*)d_in[4];
    const float* wq = (const float*)d_in[5];
    const float* wk = (const float*)d_in[6];
    const float* wv = (const float*)d_in[7];
    const float* wo = (const float*)d_in[8];
    const float* attn_norm_w = (const float*)d_in[9];
    const float* ffn_norm_w = (const float*)d_in[10];
    const float* w1 = (const float*)d_in[11];
    const float* w2 = (const float*)d_in[12];
    const float* w3 = (const float*)d_in[13];
    const float* final_norm_w = (const float*)d_in[14];
    const float* out_w = (const float*)d_in[15];
    float* out = (float*)d_out;

    const size_t SD = (size_t)S_LEN * DIM;
    const size_t SKV = (size_t)S_LEN * NKV * HD;

    char* p = (char*)d_ws;
    auto take = [&](size_t bytes) { char* r = p; p += (bytes + 255) & ~(size_t)255; return r; };
    float* h            = (float*)take(SD * 4);
    unsigned short* xnb = (unsigned short*)take(SD * 2);
    char* uni = p;
    float* qkvf         = (float*)uni;                                  // 16 MB
    unsigned short* qb  = (unsigned short*)(uni + 17039360);            // 4 MB
    unsigned short* kb  = qb + SD;                                      // 2 MB
    unsigned short* vb  = kb + SKV;                                     // 2 MB
    unsigned short* vT  = vb + SKV;                                     // 2 MB
    unsigned short* ybv = vT + SKV;                                     // 4 MB
    unsigned short* gu  = ybv + SD;                                     // 23 MB
    unsigned short* wT  = gu + (size_t)S_LEN * 5632;                    // 11.5 MB
    unsigned short* owT = (unsigned short*)uni;                         // 65.5 MB (final phase)

    embed_kernel<<<S_LEN, 256, 0, stream>>>(tokens, tok_emb, h);
    for (int l = 0; l < 2; ++l) {
        rmsnorm_kernel<<<S_LEN, 256, 0, stream>>>(h, attn_norm_w + l * DIM, xnb);
        transpose_w<<<dim3(16, 16), 256, 0, stream>>>(wq + (size_t)l * DIM * 1024, wT, DIM, 1024);
        transpose_w<<<dim3(8, 16), 256, 0, stream>>>(wk + (size_t)l * DIM * 512, wT + (size_t)1024 * DIM, DIM, 512);
        transpose_w<<<dim3(8, 16), 256, 0, stream>>>(wv + (size_t)l * DIM * 512, wT + (size_t)1536 * DIM, DIM, 512);
        gemm_tn<<<dim3(16, 16), 256, 0, stream>>>(xnb, DIM, wT, qkvf, nullptr, nullptr, 2048, DIM);
        rope_kernel<<<dim3(S_LEN, 32), 64, 0, stream>>>(qkvf, freqs_cos, freqs_sin, qb, kb, vb, out, l);
        transpose_v<<<dim3(8, 32), 256, 0, stream>>>(vb, vT);
        attn_kernel<<<dim3(S_LEN / 16, NH), 64, 0, stream>>>(qb, kb, vT, ybv);
        transpose_w<<<dim3(16, 16), 256, 0, stream>>>(wo + (size_t)l * 1024 * DIM, wT, 1024, DIM);
        gemm_tn<<<dim3(16, 8), 256, 0, stream>>>(ybv, 1024, wT, h, nullptr, h, DIM, 1024);
        rmsnorm_kernel<<<S_LEN, 256, 0, stream>>>(h, ffn_norm_w + l * DIM, xnb);
        transpose_w<<<dim3(44, 16), 256, 0, stream>>>(w1 + (size_t)l * DIM * HID, wT, DIM, HID);
        transpose_w<<<dim3(44, 16), 256, 0, stream>>>(w3 + (size_t)l * DIM * HID, wT + (size_t)HID * DIM, DIM, HID);
        gemm8<<<dim3(8, 22), 512, 0, stream>>>(xnb, wT, nullptr, gu, 5632, DIM);
        silu_mul_kernel<<<(S_LEN * 352) / 256, 256, 0, stream>>>(gu);
        transpose_w<<<dim3(16, 44), 256, 0, stream>>>(w2 + (size_t)l * HID * 1024, wT, HID, 1024);
        gemm_tn<<<dim3(16, 8), 256, 0, stream>>>(gu, 5632, wT, h, nullptr, h, DIM, HID);
    }
    rmsnorm_kernel<<<S_LEN, 256, 0, stream>>>(h, final_norm_w, xnb);
    transpose_w<<<dim3(500, 16), 256, 0, stream>>>(out_w, owT, DIM, 32000);
    gemm8<<<dim3(8, 125), 512, 0, stream>>>(xnb, owT, out, nullptr, 32000, DIM);
}